// Round 9
// baseline (202.358 us; speedup 1.0000x reference)
//
#include <hip/hip_runtime.h>
#include <hip/hip_bf16.h>
#include <stdint.h>

// B=8, N=1024, I=256, O=256, R=8
// out[b,dst,o] = (sum_{src,r} adj[b,src,dst,r] * f[b,src,r,o]) / clip(sum adj, 1e-16)
//
//  prep : x fp32->bf16; weight -> W_t[o*8+r][i] bf16
//  k1   : f_t[b][o][k=src*8+r] = W_t @ x^T (8B vector stores)
//  k2   : pout = adj^T @ f_t. MT=64 x NT=128, KS=2 -> 512 blocks x 512 thr
//         (8 waves 2m x 4o), KT=64 (8 src), 2 blocks/CU, LDS 48KB.
//         R8->R9: BOTH operands reg-staged (global->VGPR->ds_write), so barriers
//         carry ONLY lgkmcnt(0) — the vmem FIFO is never drained by a fence.
//         Prefetch depth: adj 4 slots (3-round cover for HBM ~900-1500cyc),
//         f_t 3 slots (2-round cover, L2/L3). 12-step unrolled macro keeps all
//         buffer/register indices compile-time. Fused fp32 denom.
//  k3   : sum split-K partials, normalize.

typedef float          floatx4  __attribute__((ext_vector_type(4)));
typedef short          shortx8  __attribute__((ext_vector_type(8)));
typedef unsigned short ushortx4 __attribute__((ext_vector_type(4)));
typedef unsigned short ushortx8 __attribute__((ext_vector_type(8)));
typedef unsigned int   uintx2   __attribute__((ext_vector_type(2)));
typedef unsigned int   uintx4   __attribute__((ext_vector_type(4)));

__device__ __forceinline__ unsigned short f2bf(float f) {
  union { float f; unsigned int u; } v; v.f = f;
  unsigned int u = v.u + 0x7FFFu + ((v.u >> 16) & 1u);  // RNE
  return (unsigned short)(u >> 16);
}

__device__ __forceinline__ unsigned int pkbf(float a, float b) {  // 2 f32 -> packed bf16x2
  __hip_bfloat16 ha = __float2bfloat16(a), hb = __float2bfloat16(b);
  unsigned short ua, ub;
  __builtin_memcpy(&ua, &ha, 2); __builtin_memcpy(&ub, &hb, 2);
  return (unsigned int)ua | ((unsigned int)ub << 16);
}

#define MEMFENCE asm volatile("" ::: "memory")

// ---------------- merged prep ----------------
__global__ __launch_bounds__(256) void prep_xw(const float* __restrict__ x,
                                               const float* __restrict__ w,
                                               unsigned short* __restrict__ xbf,
                                               unsigned short* __restrict__ wt) {
  int bid = blockIdx.x;
  if (bid < 1024) {                                // x: 262144 threads x 8 elems
    int t = bid * 256 + threadIdx.x;
    const float4* p = (const float4*)x + (size_t)t * 2;
    float4 a = p[0], b4 = p[1];
    ushortx8 o;
    o[0] = f2bf(a.x);  o[1] = f2bf(a.y);  o[2] = f2bf(a.z);  o[3] = f2bf(a.w);
    o[4] = f2bf(b4.x); o[5] = f2bf(b4.y); o[6] = f2bf(b4.z); o[7] = f2bf(b4.w);
    *(ushortx8*)(xbf + (size_t)t * 8) = o;
  } else {                                         // w: 524288 scalar
    int id = (bid - 1024) * 256 + threadIdx.x;
    int r = id >> 16, i = (id >> 8) & 255, o = id & 255;
    float v = w[((size_t)(r * 256 + i) << 8) + o];
    wt[((size_t)(o * 8 + r) << 8) + i] = f2bf(v);
  }
}

// ---------------- kernel 1: f_t = x @ W (operand-swapped) ----------------
__global__ __launch_bounds__(256) void k1_gemm(const unsigned short* __restrict__ xbf,
                                               const unsigned short* __restrict__ wt,
                                               unsigned short* __restrict__ ft) {
  int bid = blockIdx.x;                            // 16 p-tiles x 64 q-tiles
  int p0 = (bid & 15) * 128, q0 = (bid >> 4) * 128;
  int l = threadIdx.x & 63, w = threadIdx.x >> 6;
  int lr = l & 15, lg = l >> 4;
  int pw = p0 + (w >> 1) * 64, qw = q0 + (w & 1) * 64;

  floatx4 acc[4][4] = {};
#pragma unroll
  for (int ks = 0; ks < 8; ++ks) {                 // K = 256 = 8 * 32
    shortx8 a[4], b[4];
#pragma unroll
    for (int pi = 0; pi < 4; ++pi)
      a[pi] = *(const shortx8*)(wt + (size_t)(pw + pi * 16 + lr) * 256 + ks * 32 + lg * 8);
#pragma unroll
    for (int qi = 0; qi < 4; ++qi)
      b[qi] = *(const shortx8*)(xbf + (size_t)(qw + qi * 16 + lr) * 256 + ks * 32 + lg * 8);
#pragma unroll
    for (int pi = 0; pi < 4; ++pi)
#pragma unroll
      for (int qi = 0; qi < 4; ++qi)
        acc[pi][qi] = __builtin_amdgcn_mfma_f32_16x16x32_bf16(a[pi], b[qi], acc[pi][qi], 0, 0, 0);
  }
  // row(n') = pw+pi*16+lg*4+reg -> (o, r); col(m) = qw+qi*16+lr -> (b8, src)
#pragma unroll
  for (int pi = 0; pi < 4; ++pi) {
    int nbase = pw + pi * 16 + lg * 4;
    int o = nbase >> 3, rb = nbase & 7;
#pragma unroll
    for (int qi = 0; qi < 4; ++qi) {
      int m = qw + qi * 16 + lr;
      int b8 = m >> 10, src = m & 1023;
      ushortx4 h;
      h[0] = f2bf(acc[pi][qi][0]); h[1] = f2bf(acc[pi][qi][1]);
      h[2] = f2bf(acc[pi][qi][2]); h[3] = f2bf(acc[pi][qi][3]);
      *(ushortx4*)(ft + ((size_t)(b8 * 256 + o) << 13) + src * 8 + rb) = h;
    }
  }
}

// ---------------- kernel 2: pout = adj^T @ f_t (+ denom) ----------------
// 512 blocks x 512 thr (8 waves, 2m x 4o). Block: b, 64 dst, 128 o, K-half.
#define ASZ (64 * 64)     // 8KB per A buffer (shorts)
#define BSZ (128 * 64)    // 16KB per B buffer (shorts)
__global__ __launch_bounds__(512, 4) void k2_gemm(const float* __restrict__ adj,
                                                  const unsigned short* __restrict__ ft,
                                                  float* __restrict__ pout,
                                                  float* __restrict__ dpart) {
  __shared__ __align__(16) unsigned short Alds[2 * ASZ];  // 16KB
  __shared__ __align__(16) unsigned short Blds[2 * BSZ];  // 32KB

  int bid = blockIdx.x;
  int b = bid & 7;                     // XCD pin
  int o0 = ((bid >> 3) & 1) * 128;     // (bid, bid+8) share the same adj slice on one XCD
  int kc = (bid >> 4) & 1;             // split-K half
  int dst0 = (bid >> 5) * 64;          // 16 dst-tiles

  int t = threadIdx.x, l = t & 63, w = t >> 6;     // 8 waves
  int lr = l & 15, lg = l >> 4;
  int wm = w >> 2, wo = w & 3;                     // wave -> (dst-half, o-quarter)

  // A-staging: thread -> dst_l (0..63), r-half, 2 src rows (sA, sA+4)
  int dst_l = (t >> 1) & 63;
  int rh = (t & 1) * 4;
  int sA = t >> 7;                     // 0..3

  const size_t adj_b = (size_t)b << 23;
  const unsigned short* ftb = ft + ((size_t)b << 21);
  const int src_base = kc * 512;

  float d0 = 0.f, d1 = 0.f;
  floatx4 acc[2][2] = {};
  float4 av0[2], av1[2], av2[2], av3[2];           // adj prefetch, depth 4
  uintx4 bv0[2], bv1[2], bv2[2];                   // f_t prefetch, depth 3

  auto A_load = [&](int kt, float4* v) {
#pragma unroll
    for (int j = 0; j < 2; ++j) {
      int src = src_base + kt * 8 + sA + j * 4;
      v[j] = *(const float4*)(adj + adj_b + ((size_t)src << 13)
                              + ((size_t)(dst0 + dst_l) << 3) + rh);
    }
  };
  auto A_store = [&](int buf, const float4* v) {
#pragma unroll
    for (int j = 0; j < 2; ++j) {
      int src_l = sA + j * 4;
      float4 q = v[j];
      d0 += q.x + q.z; d1 += q.y + q.w;
      uintx2 h; h[0] = pkbf(q.x, q.y); h[1] = pkbf(q.z, q.w);
      int slot = src_l ^ (dst_l & 7);
      *(uintx2*)&Alds[buf * ASZ + dst_l * 64 + slot * 8 + rh] = h;
    }
  };
  auto B_load = [&](int kt, uintx4* v) {           // linear chunk (l&7)
    int kbase = (src_base + kt * 8) * 8;
#pragma unroll
    for (int i = 0; i < 2; ++i) {
      int orow = o0 + w * 16 + i * 8 + (l >> 3);
      v[i] = *(const uintx4*)(ftb + ((size_t)orow << 13) + kbase + ((l & 7) << 3));
    }
  };
  auto B_store = [&](int buf, const uintx4* v) {   // swizzled chunk (l&7)^(row&7)
#pragma unroll
    for (int i = 0; i < 2; ++i) {
      int row = w * 16 + i * 8 + (l >> 3);         // row&7 == l>>3
      int swc = (l & 7) ^ (l >> 3);
      *(uintx4*)&Blds[buf * BSZ + row * 64 + swc * 8] = v[i];
    }
  };
  auto compute = [&](int buf) {
#pragma unroll
    for (int s = 0; s < 2; ++s) {
      int slotbase = s * 4 + lg;
      shortx8 af[2], bfr[2];
#pragma unroll
      for (int mi = 0; mi < 2; ++mi) {
        int arow = wm * 32 + mi * 16 + lr;
        af[mi] = *(const shortx8*)&Alds[buf * ASZ + arow * 64 + ((slotbase ^ (arow & 7)) << 3)];
      }
#pragma unroll
      for (int ni = 0; ni < 2; ++ni) {
        int brow = wo * 32 + ni * 16 + lr;
        bfr[ni] = *(const shortx8*)&Blds[buf * BSZ + brow * 64 + ((slotbase ^ (brow & 7)) << 3)];
      }
#pragma unroll
      for (int mi = 0; mi < 2; ++mi)
#pragma unroll
        for (int ni = 0; ni < 2; ++ni)
          acc[mi][ni] = __builtin_amdgcn_mfma_f32_16x16x32_bf16(af[mi], bfr[ni], acc[mi][ni], 0, 0, 0);
    }
  };

#define STEP(kt, AVL, AVS, BVL, BVS, CUR, NXT, ISSA, ISSB, ST)         \
  {                                                                    \
    if (ISSA) A_load((kt) + 4, AVL);                                   \
    if (ISSB) B_load((kt) + 3, BVL);                                   \
    if (ST) { A_store(NXT, AVS); B_store(NXT, BVS); }                  \
    compute(CUR);                                                      \
    if (ST) {                                                          \
      asm volatile("s_waitcnt lgkmcnt(0)" ::: "memory");               \
      __builtin_amdgcn_s_barrier();                                    \
      MEMFENCE;                                                        \
    }                                                                  \
  }

  // ---- prologue: fill register pipeline; stage kt0 into LDS buf0 ----
  A_load(0, av0); A_load(1, av1); A_load(2, av2); A_load(3, av3);
  B_load(0, bv0); B_load(1, bv1); B_load(2, bv2);
  A_store(0, av0); B_store(0, bv0);
  asm volatile("s_waitcnt lgkmcnt(0)" ::: "memory");
  __builtin_amdgcn_s_barrier();
  MEMFENCE;

  // ---- main loop: kt 0..59 in 5 x 12-step macro (all indices compile-time) ----
  for (int kt0 = 0; kt0 < 60; kt0 += 12) {
    STEP(kt0 + 0,  av0, av1, bv0, bv1, 0, 1, 1, 1, 1);
    STEP(kt0 + 1,  av1, av2, bv1, bv2, 1, 0, 1, 1, 1);
    STEP(kt0 + 2,  av2, av3, bv2, bv0, 0, 1, 1, 1, 1);
    STEP(kt0 + 3,  av3, av0, bv0, bv1, 1, 0, 1, 1, 1);
    STEP(kt0 + 4,  av0, av1, bv1, bv2, 0, 1, 1, 1, 1);
    STEP(kt0 + 5,  av1, av2, bv2, bv0, 1, 0, 1, 1, 1);
    STEP(kt0 + 6,  av2, av3, bv0, bv1, 0, 1, 1, 1, 1);
    STEP(kt0 + 7,  av3, av0, bv1, bv2, 1, 0, 1, 1, 1);
    STEP(kt0 + 8,  av0, av1, bv2, bv0, 0, 1, 1, 1, 1);
    STEP(kt0 + 9,  av1, av2, bv0, bv1, 1, 0, 1, 1, 1);
    STEP(kt0 + 10, av2, av3, bv1, bv2, 0, 1, 1, 1, 1);
    STEP(kt0 + 11, av3, av0, bv2, bv0, 1, 0, 1, 1, 1);
  }
  // ---- tail: kt 60..63 ----
  STEP(60, av0, av1, bv0, bv1, 0, 1, 0, 1, 1);
  STEP(61, av1, av2, bv1, bv2, 1, 0, 0, 0, 1);
  STEP(62, av2, av3, bv2, bv0, 0, 1, 0, 0, 1);
  STEP(63, av3, av0, bv0, bv1, 1, 0, 0, 0, 0);
#undef STEP
  __syncthreads();                     // protect Alds overlay

  // ---- denom reduction (deterministic): 8 partials per dst row ----
  float* dsf = (float*)Alds;
  dsf[t] = d0 + d1;
  __syncthreads();
  if (t < 64) {
    float s = 0.f;
#pragma unroll
    for (int sl = 0; sl < 4; ++sl) {
      s += dsf[sl * 128 + t * 2];
      s += dsf[sl * 128 + t * 2 + 1];
    }
    dpart[kc * 8192 + (b << 10) + dst0 + t] = s;
  }

  // ---- write partials ----
#pragma unroll
  for (int mi = 0; mi < 2; ++mi) {
#pragma unroll
    for (int reg = 0; reg < 4; ++reg) {
      int row = dst0 + wm * 32 + mi * 16 + lg * 4 + reg;
#pragma unroll
      for (int ni = 0; ni < 2; ++ni) {
        int col = o0 + wo * 32 + ni * 16 + lr;
        pout[(size_t)kc * 2097152 + (((size_t)b << 10) + row) * 256 + col] = acc[mi][ni][reg];
      }
    }
  }
}

// ---------------- kernel 3: split-K reduce + normalize ----------------
__global__ __launch_bounds__(256) void k3_reduce(const float* __restrict__ pout,
                                                 const float* __restrict__ dpart,
                                                 float* __restrict__ outp) {
  int bid = blockIdx.x;              // b*1024 + dst
  size_t base = (size_t)bid * 256 + threadIdx.x;
  float v = pout[base] + pout[2097152 + base];
  float d = dpart[bid] + dpart[8192 + bid];
  outp[base] = v / fmaxf(d, 1e-16f);
}

// ---------------- launch ----------------
extern "C" void kernel_launch(void* const* d_in, const int* in_sizes, int n_in,
                              void* d_out, int out_size, void* d_ws, size_t ws_size,
                              hipStream_t stream) {
  const float* x   = (const float*)d_in[0];
  const float* adj = (const float*)d_in[1];
  const float* w   = (const float*)d_in[2];
  float* out = (float*)d_out;

  char* ws = (char*)d_ws;
  unsigned short* ft  = (unsigned short*)(ws);              // 32 MB
  unsigned short* xbf = (unsigned short*)(ws + 33554432);   //  4 MB
  unsigned short* wt  = (unsigned short*)(ws + 37748736);   //  1 MB
  float* pout  = (float*)(ws + 38797312);                   // 16 MB
  float* dpart = (float*)(ws + 55574528);                   // 64 KB

  prep_xw<<<3072, 256, 0, stream>>>(x, w, xbf, wt);
  k1_gemm<<<1024, 256, 0, stream>>>(xbf, wt, ft);
  k2_gemm<<<512, 512, 0, stream>>>(adj, ft, pout, dpart);
  k3_reduce<<<8192, 256, 0, stream>>>(pout, dpart, out);
}

// Round 11
// 173.407 us; speedup vs baseline: 1.1670x; 1.1670x over previous
//
#include <hip/hip_runtime.h>
#include <hip/hip_bf16.h>
#include <stdint.h>

// B=8, N=1024, I=256, O=256, R=8
// out[b,dst,o] = (sum_{src,r} adj[b,src,dst,r] * f[b,src,r,o]) / clip(sum adj, 1e-16)
//
//  prep : x fp32->bf16; weight -> W_t[o*8+r][i] bf16
//  k1   : f_t[b][o][k=src*8+r] = W_t @ x^T (8B vector stores)
//  k2   : pout = adj^T @ f_t. MT=64 x NT=128, KS=2 -> 512 blocks x 512 thr
//         (8 waves 2m x 4o), KT=64, 2 blocks/CU.
//         A (adj) direct global->register fragments (32B contiguous = 8 r),
//         depth-2 prefetch, cvt to bf16 in-reg. B via global_load_lds 3-buffer.
//         R10->R11 fix: fence = vmcnt(10) = per-step batch size, PROVABLY safe
//         under any compiler reordering of vmem issue (R10's vmcnt(18) assumed
//         source order; race corrupted B tiles -> absmax 0.085). Prologue/tail
//         drain vmcnt(0) (one-time). sched_barrier(0) pins B-first per step.
//  k3   : sum split-K partials, normalize.

typedef float          floatx4  __attribute__((ext_vector_type(4)));
typedef short          shortx8  __attribute__((ext_vector_type(8)));
typedef unsigned short ushortx4 __attribute__((ext_vector_type(4)));
typedef unsigned short ushortx8 __attribute__((ext_vector_type(8)));

__device__ __forceinline__ unsigned short f2bf(float f) {
  union { float f; unsigned int u; } v; v.f = f;
  unsigned int u = v.u + 0x7FFFu + ((v.u >> 16) & 1u);  // RNE
  return (unsigned short)(u >> 16);
}

__device__ __forceinline__ unsigned int pkbf(float a, float b) {
  return ((unsigned int)f2bf(a)) | (((unsigned int)f2bf(b)) << 16);
}

__device__ __forceinline__ shortx8 cvt8(float4 a, float4 b) {
  union { unsigned int u[4]; shortx8 s; } r;
  r.u[0] = pkbf(a.x, a.y); r.u[1] = pkbf(a.z, a.w);
  r.u[2] = pkbf(b.x, b.y); r.u[3] = pkbf(b.z, b.w);
  return r.s;
}

__device__ __forceinline__ void gload16(const void* g, void* l) {
  __builtin_amdgcn_global_load_lds((__attribute__((address_space(1))) void*)g,
                                   (__attribute__((address_space(3))) void*)l,
                                   16, 0, 0);
}

// ---------------- merged prep ----------------
__global__ __launch_bounds__(256) void prep_xw(const float* __restrict__ x,
                                               const float* __restrict__ w,
                                               unsigned short* __restrict__ xbf,
                                               unsigned short* __restrict__ wt) {
  int bid = blockIdx.x;
  if (bid < 1024) {                                // x: 262144 threads x 8 elems
    int t = bid * 256 + threadIdx.x;
    const float4* p = (const float4*)x + (size_t)t * 2;
    float4 a = p[0], b4 = p[1];
    ushortx8 o;
    o[0] = f2bf(a.x);  o[1] = f2bf(a.y);  o[2] = f2bf(a.z);  o[3] = f2bf(a.w);
    o[4] = f2bf(b4.x); o[5] = f2bf(b4.y); o[6] = f2bf(b4.z); o[7] = f2bf(b4.w);
    *(ushortx8*)(xbf + (size_t)t * 8) = o;
  } else {                                         // w: 524288 scalar
    int id = (bid - 1024) * 256 + threadIdx.x;
    int r = id >> 16, i = (id >> 8) & 255, o = id & 255;
    float v = w[((size_t)(r * 256 + i) << 8) + o];
    wt[((size_t)(o * 8 + r) << 8) + i] = f2bf(v);
  }
}

// ---------------- kernel 1: f_t = x @ W (operand-swapped) ----------------
__global__ __launch_bounds__(256) void k1_gemm(const unsigned short* __restrict__ xbf,
                                               const unsigned short* __restrict__ wt,
                                               unsigned short* __restrict__ ft) {
  int bid = blockIdx.x;                            // 16 p-tiles x 64 q-tiles
  int p0 = (bid & 15) * 128, q0 = (bid >> 4) * 128;
  int l = threadIdx.x & 63, w = threadIdx.x >> 6;
  int lr = l & 15, lg = l >> 4;
  int pw = p0 + (w >> 1) * 64, qw = q0 + (w & 1) * 64;

  floatx4 acc[4][4] = {};
#pragma unroll
  for (int ks = 0; ks < 8; ++ks) {                 // K = 256 = 8 * 32
    shortx8 a[4], b[4];
#pragma unroll
    for (int pi = 0; pi < 4; ++pi)
      a[pi] = *(const shortx8*)(wt + (size_t)(pw + pi * 16 + lr) * 256 + ks * 32 + lg * 8);
#pragma unroll
    for (int qi = 0; qi < 4; ++qi)
      b[qi] = *(const shortx8*)(xbf + (size_t)(qw + qi * 16 + lr) * 256 + ks * 32 + lg * 8);
#pragma unroll
    for (int pi = 0; pi < 4; ++pi)
#pragma unroll
      for (int qi = 0; qi < 4; ++qi)
        acc[pi][qi] = __builtin_amdgcn_mfma_f32_16x16x32_bf16(a[pi], b[qi], acc[pi][qi], 0, 0, 0);
  }
  // row(n') = pw+pi*16+lg*4+reg -> (o, r); col(m) = qw+qi*16+lr -> (b8, src)
#pragma unroll
  for (int pi = 0; pi < 4; ++pi) {
    int nbase = pw + pi * 16 + lg * 4;
    int o = nbase >> 3, rb = nbase & 7;
#pragma unroll
    for (int qi = 0; qi < 4; ++qi) {
      int m = qw + qi * 16 + lr;
      int b8 = m >> 10, src = m & 1023;
      ushortx4 h;
      h[0] = f2bf(acc[pi][qi][0]); h[1] = f2bf(acc[pi][qi][1]);
      h[2] = f2bf(acc[pi][qi][2]); h[3] = f2bf(acc[pi][qi][3]);
      *(ushortx4*)(ft + ((size_t)(b8 * 256 + o) << 13) + src * 8 + rb) = h;
    }
  }
}

// ---------------- kernel 2: pout = adj^T @ f_t (+ denom) ----------------
// 512 blocks x 512 thr (8 waves, 2m x 4o). Block: b, 64 dst, 128 o, K-half.
#define BSZ (128 * 64)    // 16KB per B buffer (shorts)
__global__ __launch_bounds__(512, 4) void k2_gemm(const float* __restrict__ adj,
                                                  const unsigned short* __restrict__ ft,
                                                  float* __restrict__ pout,
                                                  float* __restrict__ dpart) {
  __shared__ __align__(16) unsigned short Blds[3 * BSZ];  // 48KB (B only; no A LDS)

  int bid = blockIdx.x;
  int b = bid & 7;                     // XCD pin
  int o0 = ((bid >> 3) & 1) * 128;     // 2 o-tiles
  int kc = (bid >> 4) & 1;             // split-K half
  int dst0 = (bid >> 5) * 64;          // 16 dst-tiles

  int t = threadIdx.x, l = t & 63, w = t >> 6;     // 8 waves
  int lr = l & 15, lg = l >> 4;
  int wm = w >> 2, wo = w & 3;                     // wave -> (dst-half, o-quarter)
  bool wq0 = (wo == 0);                            // denom-owning waves (w=0, w=4)

  const int src_base = kc * 512;
  // A direct addressing: adj[b][src][dst][r]; frag(mi,s,j) for lane (lr,lg):
  //   src = src_base + kt*8 + s*4 + lg ; dst = dst0 + wm*32 + mi*16 + lr ; r = j*4..+4
  const float* adjp = adj + ((size_t)b << 23) + ((size_t)src_base << 13)
                    + ((size_t)(dst0 + wm * 32 + lr) << 3) + ((size_t)lg << 13);
  const unsigned short* ftb = ft + ((size_t)b << 21);

  float dd[2] = {0.f, 0.f};            // denom partials (rows mi*16+lr), wq0 only
  floatx4 acc[2][2] = {};
  float4 aE[2][2][2], aO[2][2][2];     // A frags [mi][s][j], even/odd kt parity

  auto A_load = [&](int kt, float4 (&v)[2][2][2]) {
#pragma unroll
    for (int mi = 0; mi < 2; ++mi)
#pragma unroll
      for (int s = 0; s < 2; ++s)
#pragma unroll
        for (int j = 0; j < 2; ++j)
          v[mi][s][j] = *(const float4*)(adjp + (size_t)kt * 65536
                                         + s * 32768 + mi * 128 + j * 4);
  };
  auto B_stage = [&](int kt, int buf) {            // 2 gload16/wave, rows w*16..+15
    int kbase = (src_base + kt * 8) * 8;
    int csw = (l & 7) ^ (l >> 3);                  // pre-swizzled source chunk
#pragma unroll
    for (int i = 0; i < 2; ++i) {
      int orow = w * 16 + i * 8 + (l >> 3);
      const unsigned short* g = ftb + ((size_t)(o0 + orow) << 13) + kbase + (csw << 3);
      gload16(g, &Blds[buf * BSZ + (w * 16 + i * 8) * 64]);
    }
  };

#define STEP(kt, C0, C1, C2, AC, ISS, ST)                                        \
  {                                                                              \
    if (ISS) B_stage((kt) + 2, C2);                                              \
    __builtin_amdgcn_sched_barrier(0);                                           \
    shortx8 af[2][2];                                                            \
    _Pragma("unroll") for (int s = 0; s < 2; ++s)                                \
      _Pragma("unroll") for (int mi = 0; mi < 2; ++mi) {                         \
        float4 p = AC[mi][s][0], q = AC[mi][s][1];                               \
        af[s][mi] = cvt8(p, q);                                                  \
        if (wq0) dd[mi] += ((p.x + p.y) + (p.z + p.w)) + ((q.x + q.y) + (q.z + q.w)); \
      }                                                                          \
    if (ISS) A_load((kt) + 2, AC);                                               \
    _Pragma("unroll") for (int s = 0; s < 2; ++s) {                              \
      int slotbase = s * 4 + lg;                                                 \
      shortx8 bfr[2];                                                            \
      _Pragma("unroll") for (int ni = 0; ni < 2; ++ni) {                         \
        int brow = wo * 32 + ni * 16 + lr;                                       \
        bfr[ni] = *(const shortx8*)&Blds[(C0) * BSZ + brow * 64 + ((slotbase ^ (brow & 7)) << 3)]; \
      }                                                                          \
      _Pragma("unroll") for (int mi = 0; mi < 2; ++mi)                           \
        _Pragma("unroll") for (int ni = 0; ni < 2; ++ni)                         \
          acc[mi][ni] = __builtin_amdgcn_mfma_f32_16x16x32_bf16(af[s][mi], bfr[ni], acc[mi][ni], 0, 0, 0); \
    }                                                                            \
    if (ST) {                                                                    \
      if (ISS) { asm volatile("s_waitcnt vmcnt(10)" ::: "memory"); }             \
      else     { asm volatile("s_waitcnt vmcnt(0)"  ::: "memory"); }             \
      __builtin_amdgcn_s_barrier();                                              \
      asm volatile("" ::: "memory");                                             \
    }                                                                            \
  }

  // ---- prologue: B(0),B(1) staged; A(0),A(1) in regs; full drain (once) ----
  B_stage(0, 0);
  B_stage(1, 1);
  __builtin_amdgcn_sched_barrier(0);
  A_load(0, aE);
  A_load(1, aO);
  asm volatile("s_waitcnt vmcnt(0)" ::: "memory");
  __builtin_amdgcn_s_barrier();
  asm volatile("" ::: "memory");

  // ---- main loop: kt 0..59, 6-step macro (LCM of buf period 3, parity 2) ----
  for (int kt0 = 0; kt0 < 60; kt0 += 6) {
    STEP(kt0 + 0, 0, 1, 2, aE, 1, 1);
    STEP(kt0 + 1, 1, 2, 0, aO, 1, 1);
    STEP(kt0 + 2, 2, 0, 1, aE, 1, 1);
    STEP(kt0 + 3, 0, 1, 2, aO, 1, 1);
    STEP(kt0 + 4, 1, 2, 0, aE, 1, 1);
    STEP(kt0 + 5, 2, 0, 1, aO, 1, 1);
  }
  // ---- tail: kt 60..63 ----
  STEP(60, 0, 1, 2, aE, 1, 1);
  STEP(61, 1, 2, 0, aO, 1, 1);
  STEP(62, 2, 0, 1, aE, 0, 1);   // vmcnt(0): drains B(63); A(63) reg-waited next
  STEP(63, 0, 1, 2, aO, 0, 0);
#undef STEP

  // ---- denom: in-register reduce over lg (lanes l, l^16, l^32, l^48) ----
  if (wq0) {
#pragma unroll
    for (int mi = 0; mi < 2; ++mi) {
      dd[mi] += __shfl_xor(dd[mi], 16);
      dd[mi] += __shfl_xor(dd[mi], 32);
    }
    if (l < 16) {
      dpart[kc * 8192 + (b << 10) + dst0 + wm * 32 + lr]      = dd[0];
      dpart[kc * 8192 + (b << 10) + dst0 + wm * 32 + 16 + lr] = dd[1];
    }
  }

  // ---- write partials ----
#pragma unroll
  for (int mi = 0; mi < 2; ++mi) {
#pragma unroll
    for (int reg = 0; reg < 4; ++reg) {
      int row = dst0 + wm * 32 + mi * 16 + lg * 4 + reg;
#pragma unroll
      for (int ni = 0; ni < 2; ++ni) {
        int col = o0 + wo * 32 + ni * 16 + lr;
        pout[(size_t)kc * 2097152 + (((size_t)b << 10) + row) * 256 + col] = acc[mi][ni][reg];
      }
    }
  }
}

// ---------------- kernel 3: split-K reduce + normalize ----------------
__global__ __launch_bounds__(256) void k3_reduce(const float* __restrict__ pout,
                                                 const float* __restrict__ dpart,
                                                 float* __restrict__ outp) {
  int bid = blockIdx.x;              // b*1024 + dst
  size_t base = (size_t)bid * 256 + threadIdx.x;
  float v = pout[base] + pout[2097152 + base];
  float d = dpart[bid] + dpart[8192 + bid];
  outp[base] = v / fmaxf(d, 1e-16f);
}

// ---------------- launch ----------------
extern "C" void kernel_launch(void* const* d_in, const int* in_sizes, int n_in,
                              void* d_out, int out_size, void* d_ws, size_t ws_size,
                              hipStream_t stream) {
  const float* x   = (const float*)d_in[0];
  const float* adj = (const float*)d_in[1];
  const float* w   = (const float*)d_in[2];
  float* out = (float*)d_out;

  char* ws = (char*)d_ws;
  unsigned short* ft  = (unsigned short*)(ws);              // 32 MB
  unsigned short* xbf = (unsigned short*)(ws + 33554432);   //  4 MB
  unsigned short* wt  = (unsigned short*)(ws + 37748736);   //  1 MB
  float* pout  = (float*)(ws + 38797312);                   // 16 MB
  float* dpart = (float*)(ws + 55574528);                   // 64 KB

  prep_xw<<<3072, 256, 0, stream>>>(x, w, xbf, wt);
  k1_gemm<<<1024, 256, 0, stream>>>(xbf, wt, ft);
  k2_gemm<<<512, 512, 0, stream>>>(adj, ft, pout, dpart);
  k3_reduce<<<8192, 256, 0, stream>>>(pout, dpart, out);
}